// Round 16
// baseline (89.660 us; speedup 1.0000x reference)
//
#include <hip/hip_runtime.h>

typedef _Float16 f16;
typedef f16   f16x8 __attribute__((ext_vector_type(8)));
typedef float f32x4 __attribute__((ext_vector_type(4)));

#define E 512
#define NT 16            /* K-steps of 32 */

// counted waitcnt + barrier (T4): N = loads allowed to stay in flight
#define WAIT_BAR(N) asm volatile("s_waitcnt vmcnt(" #N ")\n\ts_barrier" ::: "memory")
#define BAR()       asm volatile("s_barrier" ::: "memory")

// direct global->LDS async copy, 16B/lane; dst = wave-uniform base + lane*16
__device__ __forceinline__ void load_lds16(const void* g, void* l) {
    __builtin_amdgcn_global_load_lds(
        (const __attribute__((address_space(1))) unsigned int*)g,
        (__attribute__((address_space(3))) unsigned int*)l,
        16, 0, 0);
}

// ---------------------------------------------------------------------------
// Weight convert: Wq, Wo (fp32 [512][512]) -> f16 row-major copies (~1 MB)
// ---------------------------------------------------------------------------
__global__ __launch_bounds__(256)
void convert_w_kernel(const float* __restrict__ wq,
                      const float* __restrict__ wo,
                      f16* __restrict__ wq_h,
                      f16* __restrict__ wo_h) {
    int i = blockIdx.x * blockDim.x + threadIdx.x;
    const int n4 = (512 * 512) / 4;
    const float4* src; f16* dst;
    if (i < n4) { src = (const float4*)wq; dst = wq_h; }
    else        { src = (const float4*)wo; dst = wo_h; i -= n4; }
    float4 v = src[i];
    f16* p = dst + (size_t)i * 4;
    p[0] = (f16)v.x; p[1] = (f16)v.y; p[2] = (f16)v.z; p[3] = (f16)v.w;
}

// ---------------------------------------------------------------------------
// Shared GEMM template (r10-proven single-barrier schedule, UNCHANGED sync):
//   C[Mx512] = f(A) @ B^T; A fp32 row-major, B f16 row-major, C fp32.
//   per step t: WAIT_BAR(6) [stage(t) landed] -> frag reads (+transform)
//   -> 16 MFMA (swapped operands) -> BAR -> stage(cur, t+2).
// A staged fp32 via gload_lds w/ source-granule XOR swizzle (r10-verified);
// B staged f16 linear. 48KB LDS -> 3 blocks/CU. 4 waves, 64x64 wave tiles.
//
// QCOS=false: f = identity        (gemm1: qraw = x @ Wq^T; EPILOGUE ABLATION)
// QCOS=true:  f = cumprod8(cos()) applied AT FRAGMENT READ — each lane's
//   A-frag is 8 consecutive k(=f) elems aligned to 8 = exactly one head,
//   so the transform is 8 cos + 7 mul in-thread, no shuffles, no LDS pass.
//   (gemm2: out = meas @ Wo^T without ever materializing meas)
// ---------------------------------------------------------------------------
template <bool QCOS>
__global__ __launch_bounds__(256, 3)
void gemm_kernel(const float* __restrict__ X,
                 const f16* __restrict__ B,
                 float* __restrict__ Out) {
    __shared__ __align__(16) char As[2][128 * 32 * 4];  // fp32, 16KB/buf
    __shared__ __align__(16) char Bs[2][128 * 32 * 2];  // f16,   8KB/buf

    const int tid  = threadIdx.x;
    const int lane = tid & 63;
    const int wave = tid >> 6;
    const int wm = (wave >> 1) * 64;
    const int wn = (wave & 1) * 64;
    const int fr = lane & 15;
    const int kq = lane >> 4;

    const int bid = blockIdx.x;                 // grid 1024, %8==0
    const int chunk = gridDim.x >> 3;
    const int swz = (bid & 7) * chunk + (bid >> 3);
    const int m0 = (swz >> 2) * 128;
    const int n0 = (swz & 3) * 128;

    auto stage = [&](int buf, int kt) {         // 6 loads/wave: 4 A + 2 B
        const int k0 = kt * 32;
#pragma unroll
        for (int c = 0; c < 4; ++c) {           // A: 16 x 1KB chunks
            const int ch = wave * 4 + c;
            const int s = ch * 64 + lane;       // LDS granule slot
            const int row = s >> 3;
            const int g = (s & 7) ^ (row & 7);  // XOR-swizzled source granule
            const float* src = X + (size_t)(m0 + row) * E + k0 + g * 4;
            load_lds16(src, As[buf] + ch * 1024);
        }
#pragma unroll
        for (int c = 0; c < 2; ++c) {           // B: 8 x 1KB chunks, linear
            const int ch = wave * 2 + c;
            const int G = ch * 64 + lane;       // n=G>>2, colg=(G&3)*8
            const f16* src = B + (size_t)(n0 + (G >> 2)) * E + k0 + (G & 3) * 8;
            load_lds16(src, Bs[buf] + ch * 1024);
        }
    };

    f32x4 acc[4][4] = {};

    stage(0, 0);
    stage(1, 1);

#pragma unroll
    for (int t = 0; t < NT; ++t) {
        const int cur = t & 1;
        if (t + 1 < NT) { WAIT_BAR(6); } else { WAIT_BAR(0); }

        f16x8 afr[4], bfr[4];
#pragma unroll
        for (int i = 0; i < 4; ++i) {           // 2 swizzled f32x4 reads
            const int r = wm + i * 16 + fr;
            const float* base = (const float*)As[cur] + r * 32;
            const int p0 = (kq * 2) ^ (r & 7);
            const int p1 = (kq * 2 + 1) ^ (r & 7);
            f32x4 a0 = *(const f32x4*)(base + p0 * 4);   // head elems 0..3
            f32x4 a1 = *(const f32x4*)(base + p1 * 4);   // head elems 4..7
            if (QCOS) {
                // frag = one head (8 consecutive f, 8-aligned): in-thread cumprod
                float m1 = __cosf(a0[0]);
                float m2 = m1 * __cosf(a0[1]);
                float m3 = m2 * __cosf(a0[2]);
                float m4 = m3 * __cosf(a0[3]);
                float m5 = m4 * __cosf(a1[0]);
                float m6 = m5 * __cosf(a1[1]);
                float m7 = m6 * __cosf(a1[2]);
                float m8 = m7 * __cosf(a1[3]);
                afr[i] = f16x8{ (f16)m1, (f16)m2, (f16)m3, (f16)m4,
                                (f16)m5, (f16)m6, (f16)m7, (f16)m8 };
            } else {
#pragma unroll
                for (int q = 0; q < 4; ++q) {
                    afr[i][q]     = (f16)a0[q];
                    afr[i][4 + q] = (f16)a1[q];
                }
            }
        }
#pragma unroll
        for (int j = 0; j < 4; ++j)
            bfr[j] = *(const f16x8*)&((const f16*)Bs[cur])[(wn + j * 16 + fr) * 32 + kq * 8];

        // swapped operands: m = lane&15, n = (lane>>4)*4 + reg
#pragma unroll
        for (int i = 0; i < 4; ++i)
#pragma unroll
            for (int j = 0; j < 4; ++j)
                acc[i][j] = __builtin_amdgcn_mfma_f32_16x16x32_f16(
                    bfr[j], afr[i], acc[i][j], 0, 0, 0);

        BAR();
        if (t + 2 < NT) stage(cur, t + 2);      // refill just-read buffers
    }

    // raw f32x4 stores (the proven-fast gemm_o pattern; NO quantum epilogue)
#pragma unroll
    for (int i = 0; i < 4; ++i) {
        const int row = m0 + wm + i * 16 + fr;
#pragma unroll
        for (int j = 0; j < 4; ++j) {
            const int col = n0 + wn + j * 16 + kq * 4;
            *(f32x4*)&Out[(size_t)row * E + col] = acc[i][j];
        }
    }
}

// ---------------------------------------------------------------------------
extern "C" void kernel_launch(void* const* d_in, const int* in_sizes, int n_in,
                              void* d_out, int out_size, void* d_ws, size_t ws_size,
                              hipStream_t stream) {
    const float* x  = (const float*)d_in[0];
    const float* Wq = (const float*)d_in[1];
    // d_in[2]=Wk, d_in[3]=Wv: dead compute in the reference
    const float* Wo = (const float*)d_in[4];

    const int M = in_sizes[0] / E;   // 32768

    f16*   wq_h = (f16*)d_ws;                         // 512 KB
    f16*   wo_h = wq_h + 512 * 512;                   // 512 KB
    float* qraw = (float*)(wo_h + 512 * 512);         // 64 MB fp32 (ws-resident)

    convert_w_kernel<<<512, 256, 0, stream>>>(Wq, Wo, wq_h, wo_h);

    const int nblk = (M / 128) * 4;                   // 1024
    // gemm1 = r10's gemm_q MINUS the quantum epilogue (the ablation)
    gemm_kernel<false><<<nblk, 256, 0, stream>>>(x, wq_h, qraw);
    // gemm2 = quantum transform at fragment-read time (no meas buffer)
    gemm_kernel<true><<<nblk, 256, 0, stream>>>(qraw, wo_h, (float*)d_out);
}